// Round 8
// baseline (276.507 us; speedup 1.0000x reference)
//
#include <hip/hip_runtime.h>
#include <hip/hip_bf16.h>
#include <hip/hip_fp16.h>

// Problem constants (fixed by setup_inputs)
#define NROWS 4096
#define IDIM  512
#define HDIM  2048
#define ODIM  512
#define NG    8      // groups (prefix structure)
#define NCH   8      // H chunks
#define HC    256    // H per chunk
#define TM    64     // rows per main block

typedef __attribute__((ext_vector_type(8))) short short8;   // 8 bf16
typedef __attribute__((ext_vector_type(4))) float f32x4;

__device__ __forceinline__ unsigned short f2bf(float f) {
    unsigned int u = __float_as_uint(f);
    unsigned int r = (u + 0x7fffu + ((u >> 16) & 1u)) >> 16;
    return (unsigned short)r;
}

// async global->LDS, 16B per lane; lds base must be wave-uniform (HW adds lane*16)
__device__ __forceinline__ void glds16(const unsigned short* g, unsigned short* l) {
    __builtin_amdgcn_global_load_lds(
        (const __attribute__((address_space(1))) unsigned int*)g,
        (__attribute__((address_space(3))) unsigned int*)l, 16, 0, 0);
}

// ---- Prep kernel: x-convert + W1/W2 transpose-convert + counter zeroing ----
__global__ __launch_bounds__(256) void k_prep(const float* __restrict__ x,
                                              const float* __restrict__ W1,
                                              const float* __restrict__ W2,
                                              unsigned short* __restrict__ xb,
                                              unsigned short* __restrict__ w1t,
                                              unsigned short* __restrict__ w2t,
                                              int* __restrict__ cnt) {
    __shared__ float tile[64 * 68];
    const int bz = blockIdx.x;
    const int t = threadIdx.x;
    if (bz < 1024) {
        if (bz == 0 && t < 64) cnt[t] = 0;        // completion counters for k_main
        int gt = bz * 256 + t;                    // x: 262144 threads, 8 floats each
        const float4* src = reinterpret_cast<const float4*>(x) + (size_t)gt * 2;
        float4 a = src[0], b = src[1];
        unsigned short o[8] = { f2bf(a.x), f2bf(a.y), f2bf(a.z), f2bf(a.w),
                                f2bf(b.x), f2bf(b.y), f2bf(b.z), f2bf(b.w) };
        *reinterpret_cast<uint4*>(xb + (size_t)gt * 8) = *reinterpret_cast<uint4*>(o);
        return;
    }
    int b = bz - 1024;
    const float* in;
    unsigned short* out;
    int R, C, c0, r0;
    if (b < 256) {            // W1: 512x2048 -> w1t[2048][512]
        in = W1; out = w1t; R = 512; C = 2048;
        c0 = (b & 31) * 64; r0 = (b >> 5) * 64;
    } else {                  // W2: 2048x512 -> w2t[512][2048]
        b -= 256;
        in = W2; out = w2t; R = 2048; C = 512;
        c0 = (b & 7) * 64; r0 = (b >> 3) * 64;
    }
    const int tx = t & 15, ty = t >> 4;
    #pragma unroll
    for (int p = 0; p < 4; ++p) {
        int rr = p * 16 + ty;
        float4 v = *reinterpret_cast<const float4*>(&in[(size_t)(r0 + rr) * C + c0 + tx * 4]);
        tile[rr * 68 + tx * 4 + 0] = v.x;
        tile[rr * 68 + tx * 4 + 1] = v.y;
        tile[rr * 68 + tx * 4 + 2] = v.z;
        tile[rr * 68 + tx * 4 + 3] = v.w;
    }
    __syncthreads();
    #pragma unroll
    for (int p = 0; p < 4; ++p) {
        int rr = p * 16 + ty;
        int cc = tx * 4;
        ushort4 o;
        o.x = f2bf(tile[(cc + 0) * 68 + rr]);
        o.y = f2bf(tile[(cc + 1) * 68 + rr]);
        o.z = f2bf(tile[(cc + 2) * 68 + rr]);
        o.w = f2bf(tile[(cc + 3) * 68 + rr]);
        *reinterpret_cast<ushort4*>(&out[(size_t)(c0 + rr) * R + r0 + cc]) = o;
    }
}

// ---- Kernel 1: fused prefix-GEMM1^T + relu + GEMM2 + last-block reduce ----
// grid (8, 64) = 512 blocks (2/CU), 512 threads (8 waves). LDS 72KB.
// Round-5 body (best measured): W2 staged via glds16, W1 via 4-frag VGPR
// prefetch, GEMM1 transposed -> packed b64 sH writes, bias folded into acc
// init, 3 barriers/g. New: GEMM2 on 4 waves with 2x2 tiles (128 vs 192 LDS
// reads/block/g); after the g-loop the 8th-arriving block per row-tile
// reduces P (+b2) into out (replaces k_reduce kernel).
__global__ __launch_bounds__(512, 4) void k_main(const unsigned short* __restrict__ xb,   // [4096][512]
                                                 const unsigned short* __restrict__ w1t,  // [2048][512] = W1^T
                                                 const unsigned short* __restrict__ w2t,  // [512][2048] = W2^T
                                                 const float* __restrict__ b1,            // [2048]
                                                 const float* __restrict__ b2,            // [512]
                                                 __half* __restrict__ P,                  // [NCH][4096][512] fp16
                                                 int* __restrict__ cnt,                   // [64]
                                                 float* __restrict__ out) {               // [4096][512]
    __shared__ unsigned short sX[64 * 64];        // x_g  [sample][k]  8KB  (swizzled)
    __shared__ unsigned short sW[64 * 256];       // W2_g [j][k]      32KB  (swizzled)
    __shared__ unsigned short sH[64 * 256];       // h    [sample][h] 32KB  (swizzled)
    __shared__ int s_last;

    const int chunk = blockIdx.x;                 // 0..7
    const int row0  = blockIdx.y * TM;
    const int hbase = chunk * HC;

    const int t    = threadIdx.x;
    const int lane = t & 63, wv = t >> 6;         // wave 0..7
    const int l16  = lane & 15, quad = lane >> 4;

    // acc1 = S + b1 (bias folded into init); GEMM1^T layout:
    // lane holds h_local = wv*32 + ct*16 + quad*4 + r, sample col = l16
    f32x4 acc1[2][4];
    #pragma unroll
    for (int ct = 0; ct < 2; ++ct) {
        f32x4 bv;
        #pragma unroll
        for (int r = 0; r < 4; ++r)
            bv[r] = b1[hbase + wv * 32 + ct * 16 + quad * 4 + r];
        #pragma unroll
        for (int rt = 0; rt < 4; ++rt) acc1[ct][rt] = bv;
    }

    const int srow = t >> 3;                      // sX staging row (0..63)
    const int scb  = t & 7;                       // sX staging 16B-block
    __half* Pc = P + (size_t)chunk * (NROWS * ODIM);
    const unsigned short* w1p = w1t + (size_t)(hbase + wv * 32 + l16) * 512 + quad * 8;
    // GEMM2 2x2 tile assignment (waves 0..3 only)
    const int r0t = (wv >> 1) * 2;                // row-tile base 0 or 2
    const int c0t = (wv & 1) * 2;                 // col-tile base 0 or 2

    for (int g = 0; g < NG; ++g) {
        __syncthreads();                          // B0: prev GEMM2 LDS reads done
        // stage x_g (8KB) and W2_g (32KB, [64j][256k] swizzled)
        glds16(xb + (size_t)(row0 + srow) * 512 + g * 64 + ((scb ^ (srow & 7)) << 3),
               sX + (size_t)(t & ~63) * 8);
        #pragma unroll
        for (int i = 0; i < 4; ++i) {
            int slot = i * 512 + t;               // 0..2047
            int jr = slot >> 5, cb = slot & 31;
            glds16(w2t + (size_t)(g * 64 + jr) * 2048 + hbase + ((cb ^ (jr & 7)) << 3),
                   sW + (size_t)(slot & ~63) * 8);
        }
        // W1_g fragments: global -> VGPR (4 frags, survives scheduling; R6
        // showed 16-frag prefetch gets sunk into the MFMA chain -- keep small)
        short8 w1f[2][2];
        #pragma unroll
        for (int kst = 0; kst < 2; ++kst)
            #pragma unroll
            for (int ct = 0; ct < 2; ++ct)
                w1f[kst][ct] = *reinterpret_cast<const short8*>(
                    w1p + (size_t)ct * 16 * 512 + g * 64 + kst * 32);
        __syncthreads();                          // B1: staged, w1f landed

        // ---- GEMM1^T: acc1 += W1_g(A) x x_g(B) -> D[h][sample] ----
        #pragma unroll
        for (int kst = 0; kst < 2; ++kst) {
            short8 xf[4];
            #pragma unroll
            for (int rt = 0; rt < 4; ++rt) {
                int row = rt * 16 + l16;
                xf[rt] = *reinterpret_cast<const short8*>(
                    &sX[row * 64 + (((kst * 4 + quad) ^ (row & 7)) << 3)]);
            }
            #pragma unroll
            for (int ct = 0; ct < 2; ++ct)
                #pragma unroll
                for (int rt = 0; rt < 4; ++rt)
                    acc1[ct][rt] = __builtin_amdgcn_mfma_f32_16x16x32_bf16(
                        w1f[kst][ct], xf[rt], acc1[ct][rt], 0, 0, 0);
        }

        // ---- h = relu(acc1) -> sH, 4 consecutive h packed into b64 ----
        #pragma unroll
        for (int ct = 0; ct < 2; ++ct) {
            const int cb2 = wv * 4 + ct * 2 + (quad >> 1);
            #pragma unroll
            for (int rt = 0; rt < 4; ++rt) {
                const int sample = rt * 16 + l16;
                unsigned int u0 = (__float_as_uint(fmaxf(acc1[ct][rt][0], 0.f)) + 0x8000u) >> 16;
                unsigned int u1 = (__float_as_uint(fmaxf(acc1[ct][rt][1], 0.f)) + 0x8000u) & 0xFFFF0000u;
                unsigned int u2 = (__float_as_uint(fmaxf(acc1[ct][rt][2], 0.f)) + 0x8000u) >> 16;
                unsigned int u3 = (__float_as_uint(fmaxf(acc1[ct][rt][3], 0.f)) + 0x8000u) & 0xFFFF0000u;
                uint2 pk = { u0 | u1, u2 | u3 };
                *reinterpret_cast<uint2*>(
                    &sH[sample * 256 + ((cb2 ^ (sample & 7)) << 3) + (quad & 1) * 4]) = pk;
            }
        }
        __syncthreads();                          // B2: sH ready (sW staged since B1)

        // ---- GEMM2 on waves 0..3: 2x2 tiles each (4 LDS reads/kstep) ----
        if (wv < 4) {
            f32x4 acc2[2][2];
            acc2[0][0] = 0.f; acc2[0][1] = 0.f; acc2[1][0] = 0.f; acc2[1][1] = 0.f;
            #pragma unroll
            for (int kst = 0; kst < 8; ++kst) {
                short8 a[2], b[2];
                #pragma unroll
                for (int i = 0; i < 2; ++i) {
                    int arow = (r0t + i) * 16 + l16;
                    a[i] = *reinterpret_cast<const short8*>(
                        &sH[arow * 256 + (((kst * 4 + quad) ^ (arow & 7)) << 3)]);
                }
                #pragma unroll
                for (int j = 0; j < 2; ++j) {
                    int brow = (c0t + j) * 16 + l16;
                    b[j] = *reinterpret_cast<const short8*>(
                        &sW[brow * 256 + (((kst * 4 + quad) ^ (brow & 7)) << 3)]);
                }
                #pragma unroll
                for (int i = 0; i < 2; ++i)
                    #pragma unroll
                    for (int j = 0; j < 2; ++j)
                        acc2[i][j] = __builtin_amdgcn_mfma_f32_16x16x32_bf16(
                            a[i], b[j], acc2[i][j], 0, 0, 0);
            }
            #pragma unroll
            for (int i = 0; i < 2; ++i)
                #pragma unroll
                for (int j = 0; j < 2; ++j)
                    #pragma unroll
                    for (int r = 0; r < 4; ++r)
                        Pc[(size_t)(row0 + (r0t + i) * 16 + quad * 4 + r) * 512 +
                           g * 64 + (c0t + j) * 16 + l16] = __float2half(acc2[i][j][r]);
        }
    }

    // ---- last-arriving block per row-tile reduces P (+ b2) into out ----
    __threadfence();                              // release P stores
    if (t == 0) {
        int old = atomicAdd(&cnt[blockIdx.y], 1);
        s_last = (old == NCH - 1) ? 1 : 0;
    }
    __syncthreads();
    if (s_last) {
        __threadfence();                          // acquire other blocks' P
        const int colb = (t * 8) & 511;
        float4 b2a = *reinterpret_cast<const float4*>(&b2[colb]);
        float4 b2b = *reinterpret_cast<const float4*>(&b2[colb + 4]);
        #pragma unroll
        for (int i = 0; i < 8; ++i) {
            size_t off = (size_t)row0 * 512 + i * 4096 + t * 8;
            float s[8] = { b2a.x, b2a.y, b2a.z, b2a.w, b2b.x, b2b.y, b2b.z, b2b.w };
            #pragma unroll
            for (int c = 0; c < NCH; ++c) {
                uint4 raw = *reinterpret_cast<const uint4*>(
                    P + (size_t)c * (NROWS * ODIM) + off);
                const __half2* h2 = reinterpret_cast<const __half2*>(&raw);
                #pragma unroll
                for (int q = 0; q < 4; ++q) {
                    float2 f = __half22float2(h2[q]);
                    s[q * 2 + 0] += f.x;
                    s[q * 2 + 1] += f.y;
                }
            }
            *reinterpret_cast<float4*>(&out[off])     = make_float4(s[0], s[1], s[2], s[3]);
            *reinterpret_cast<float4*>(&out[off + 4]) = make_float4(s[4], s[5], s[6], s[7]);
        }
    }
}

extern "C" void kernel_launch(void* const* d_in, const int* in_sizes, int n_in,
                              void* d_out, int out_size, void* d_ws, size_t ws_size,
                              hipStream_t stream) {
    const float* x  = (const float*)d_in[0];
    const float* W1 = (const float*)d_in[1];
    const float* b1 = (const float*)d_in[2];
    const float* W2 = (const float*)d_in[3];
    const float* b2 = (const float*)d_in[4];
    float* out = (float*)d_out;

    unsigned short* xb  = (unsigned short*)d_ws;                          // 4 MB
    unsigned short* w1t = (unsigned short*)((char*)d_ws + (4u << 20));    // 2 MB
    unsigned short* w2t = (unsigned short*)((char*)d_ws + (6u << 20));    // 2 MB
    __half*         P   = (__half*)((char*)d_ws + (8u << 20));            // 32 MB fp16
    int*            cnt = (int*)((char*)d_ws + (40u << 20));              // 64 ints

    k_prep<<<1536, 256, 0, stream>>>(x, W1, W2, xb, w1t, w2t, cnt);
    k_main<<<dim3(NCH, NROWS / TM), 512, 0, stream>>>(xb, w1t, w2t, b1, b2, P, cnt, out);
}

// Round 9
// 136.503 us; speedup vs baseline: 2.0256x; 2.0256x over previous
//
#include <hip/hip_runtime.h>
#include <hip/hip_bf16.h>
#include <hip/hip_fp16.h>

// Problem constants (fixed by setup_inputs)
#define NROWS 4096
#define IDIM  512
#define HDIM  2048
#define ODIM  512
#define NG    8      // groups (prefix structure)
#define NCH   8      // H chunks
#define HC    256    // H per chunk
#define TM    64     // rows per main block

typedef __attribute__((ext_vector_type(8))) short short8;   // 8 bf16
typedef __attribute__((ext_vector_type(4))) float f32x4;

__device__ __forceinline__ unsigned short f2bf(float f) {
    unsigned int u = __float_as_uint(f);
    unsigned int r = (u + 0x7fffu + ((u >> 16) & 1u)) >> 16;
    return (unsigned short)r;
}

// async global->LDS, 16B per lane; lds base must be wave-uniform (HW adds lane*16)
__device__ __forceinline__ void glds16(const unsigned short* g, unsigned short* l) {
    __builtin_amdgcn_global_load_lds(
        (const __attribute__((address_space(1))) unsigned int*)g,
        (__attribute__((address_space(3))) unsigned int*)l, 16, 0, 0);
}

// ---- Prep kernel: fused x-convert + W1/W2 transpose-convert ----
__global__ __launch_bounds__(256) void k_prep(const float* __restrict__ x,
                                              const float* __restrict__ W1,
                                              const float* __restrict__ W2,
                                              unsigned short* __restrict__ xb,
                                              unsigned short* __restrict__ w1t,
                                              unsigned short* __restrict__ w2t) {
    __shared__ float tile[64 * 68];
    const int bz = blockIdx.x;
    const int t = threadIdx.x;
    if (bz < 1024) {
        int gt = bz * 256 + t;                    // x: 262144 threads, 8 floats each
        const float4* src = reinterpret_cast<const float4*>(x) + (size_t)gt * 2;
        float4 a = src[0], b = src[1];
        unsigned short o[8] = { f2bf(a.x), f2bf(a.y), f2bf(a.z), f2bf(a.w),
                                f2bf(b.x), f2bf(b.y), f2bf(b.z), f2bf(b.w) };
        *reinterpret_cast<uint4*>(xb + (size_t)gt * 8) = *reinterpret_cast<uint4*>(o);
        return;
    }
    int b = bz - 1024;
    const float* in;
    unsigned short* out;
    int R, C, c0, r0;
    if (b < 256) {            // W1: 512x2048 -> w1t[2048][512]
        in = W1; out = w1t; R = 512; C = 2048;
        c0 = (b & 31) * 64; r0 = (b >> 5) * 64;
    } else {                  // W2: 2048x512 -> w2t[512][2048]
        b -= 256;
        in = W2; out = w2t; R = 2048; C = 512;
        c0 = (b & 7) * 64; r0 = (b >> 3) * 64;
    }
    const int tx = t & 15, ty = t >> 4;
    #pragma unroll
    for (int p = 0; p < 4; ++p) {
        int rr = p * 16 + ty;
        float4 v = *reinterpret_cast<const float4*>(&in[(size_t)(r0 + rr) * C + c0 + tx * 4]);
        tile[rr * 68 + tx * 4 + 0] = v.x;
        tile[rr * 68 + tx * 4 + 1] = v.y;
        tile[rr * 68 + tx * 4 + 2] = v.z;
        tile[rr * 68 + tx * 4 + 3] = v.w;
    }
    __syncthreads();
    #pragma unroll
    for (int p = 0; p < 4; ++p) {
        int rr = p * 16 + ty;
        int cc = tx * 4;
        ushort4 o;
        o.x = f2bf(tile[(cc + 0) * 68 + rr]);
        o.y = f2bf(tile[(cc + 1) * 68 + rr]);
        o.z = f2bf(tile[(cc + 2) * 68 + rr]);
        o.w = f2bf(tile[(cc + 3) * 68 + rr]);
        *reinterpret_cast<ushort4*>(&out[(size_t)(c0 + rr) * R + r0 + cc]) = o;
    }
}

// ---- Kernel 1: fused prefix-GEMM1^T + relu + GEMM2 partials (fp16) ----
// grid (8, 64) = 512 blocks (2/CU), 512 threads (8 waves). LDS 72KB.
// Round-5 structure (best measured): W2 staged via glds16 (16-frag VGPR
// prefetch fails -- R6), W1 via 4-frag VGPR prefetch (works -- R5), GEMM1
// transposed -> packed b64 sH writes, bias folded into acc init, 3 barriers/g.
// GEMM2 on 4 waves with 2x2 tiles (R8-verified): 1.0 LDS read/MFMA vs 1.5,
// cuts the dominant LDS-read term ~33%. NO device-scope fences (R8 lesson:
// per-block __threadfence = L2 writeback storm, +42MB HBM, 6x regression).
__global__ __launch_bounds__(512, 4) void k_main(const unsigned short* __restrict__ xb,   // [4096][512]
                                                 const unsigned short* __restrict__ w1t,  // [2048][512] = W1^T
                                                 const unsigned short* __restrict__ w2t,  // [512][2048] = W2^T
                                                 const float* __restrict__ b1,            // [2048]
                                                 __half* __restrict__ P) {                // [NCH][4096][512] fp16
    __shared__ unsigned short sX[64 * 64];        // x_g  [sample][k]  8KB  (swizzled)
    __shared__ unsigned short sW[64 * 256];       // W2_g [j][k]      32KB  (swizzled)
    __shared__ unsigned short sH[64 * 256];       // h    [sample][h] 32KB  (swizzled)

    const int chunk = blockIdx.x;                 // 0..7
    const int row0  = blockIdx.y * TM;
    const int hbase = chunk * HC;

    const int t    = threadIdx.x;
    const int lane = t & 63, wv = t >> 6;         // wave 0..7
    const int l16  = lane & 15, quad = lane >> 4;

    // acc1 = S + b1 (bias folded into init); GEMM1^T layout:
    // lane holds h_local = wv*32 + ct*16 + quad*4 + r, sample col = l16
    f32x4 acc1[2][4];
    #pragma unroll
    for (int ct = 0; ct < 2; ++ct) {
        f32x4 bv;
        #pragma unroll
        for (int r = 0; r < 4; ++r)
            bv[r] = b1[hbase + wv * 32 + ct * 16 + quad * 4 + r];
        #pragma unroll
        for (int rt = 0; rt < 4; ++rt) acc1[ct][rt] = bv;
    }

    const int srow = t >> 3;                      // sX staging row (0..63)
    const int scb  = t & 7;                       // sX staging 16B-block
    __half* Pc = P + (size_t)chunk * (NROWS * ODIM);
    const unsigned short* w1p = w1t + (size_t)(hbase + wv * 32 + l16) * 512 + quad * 8;
    // GEMM2 2x2 tile assignment (waves 0..3 only)
    const int r0t = (wv >> 1) * 2;                // row-tile base 0 or 2
    const int c0t = (wv & 1) * 2;                 // col-tile base 0 or 2

    for (int g = 0; g < NG; ++g) {
        __syncthreads();                          // B0: prev GEMM2 LDS reads done
        // stage x_g (8KB) and W2_g (32KB, [64j][256k] swizzled)
        glds16(xb + (size_t)(row0 + srow) * 512 + g * 64 + ((scb ^ (srow & 7)) << 3),
               sX + (size_t)(t & ~63) * 8);
        #pragma unroll
        for (int i = 0; i < 4; ++i) {
            int slot = i * 512 + t;               // 0..2047
            int jr = slot >> 5, cb = slot & 31;
            glds16(w2t + (size_t)(g * 64 + jr) * 2048 + hbase + ((cb ^ (jr & 7)) << 3),
                   sW + (size_t)(slot & ~63) * 8);
        }
        // W1_g fragments: global -> VGPR (4 frags, survives scheduling)
        short8 w1f[2][2];
        #pragma unroll
        for (int kst = 0; kst < 2; ++kst)
            #pragma unroll
            for (int ct = 0; ct < 2; ++ct)
                w1f[kst][ct] = *reinterpret_cast<const short8*>(
                    w1p + (size_t)ct * 16 * 512 + g * 64 + kst * 32);
        __syncthreads();                          // B1: staged, w1f landed

        // ---- GEMM1^T: acc1 += W1_g(A) x x_g(B) -> D[h][sample] ----
        #pragma unroll
        for (int kst = 0; kst < 2; ++kst) {
            short8 xf[4];
            #pragma unroll
            for (int rt = 0; rt < 4; ++rt) {
                int row = rt * 16 + l16;
                xf[rt] = *reinterpret_cast<const short8*>(
                    &sX[row * 64 + (((kst * 4 + quad) ^ (row & 7)) << 3)]);
            }
            #pragma unroll
            for (int ct = 0; ct < 2; ++ct)
                #pragma unroll
                for (int rt = 0; rt < 4; ++rt)
                    acc1[ct][rt] = __builtin_amdgcn_mfma_f32_16x16x32_bf16(
                        w1f[kst][ct], xf[rt], acc1[ct][rt], 0, 0, 0);
        }

        // ---- h = relu(acc1) -> sH, 4 consecutive h packed into b64 ----
        #pragma unroll
        for (int ct = 0; ct < 2; ++ct) {
            const int cb2 = wv * 4 + ct * 2 + (quad >> 1);
            #pragma unroll
            for (int rt = 0; rt < 4; ++rt) {
                const int sample = rt * 16 + l16;
                unsigned int u0 = (__float_as_uint(fmaxf(acc1[ct][rt][0], 0.f)) + 0x8000u) >> 16;
                unsigned int u1 = (__float_as_uint(fmaxf(acc1[ct][rt][1], 0.f)) + 0x8000u) & 0xFFFF0000u;
                unsigned int u2 = (__float_as_uint(fmaxf(acc1[ct][rt][2], 0.f)) + 0x8000u) >> 16;
                unsigned int u3 = (__float_as_uint(fmaxf(acc1[ct][rt][3], 0.f)) + 0x8000u) & 0xFFFF0000u;
                uint2 pk = { u0 | u1, u2 | u3 };
                *reinterpret_cast<uint2*>(
                    &sH[sample * 256 + ((cb2 ^ (sample & 7)) << 3) + (quad & 1) * 4]) = pk;
            }
        }
        __syncthreads();                          // B2: sH ready (sW staged since B1)

        // ---- GEMM2 on waves 0..3: 2x2 tiles each (4 LDS reads / 4 MFMA) ----
        if (wv < 4) {
            f32x4 acc2[2][2];
            acc2[0][0] = 0.f; acc2[0][1] = 0.f; acc2[1][0] = 0.f; acc2[1][1] = 0.f;
            #pragma unroll
            for (int kst = 0; kst < 8; ++kst) {
                short8 a[2], b[2];
                #pragma unroll
                for (int i = 0; i < 2; ++i) {
                    int arow = (r0t + i) * 16 + l16;
                    a[i] = *reinterpret_cast<const short8*>(
                        &sH[arow * 256 + (((kst * 4 + quad) ^ (arow & 7)) << 3)]);
                }
                #pragma unroll
                for (int j = 0; j < 2; ++j) {
                    int brow = (c0t + j) * 16 + l16;
                    b[j] = *reinterpret_cast<const short8*>(
                        &sW[brow * 256 + (((kst * 4 + quad) ^ (brow & 7)) << 3)]);
                }
                #pragma unroll
                for (int i = 0; i < 2; ++i)
                    #pragma unroll
                    for (int j = 0; j < 2; ++j)
                        acc2[i][j] = __builtin_amdgcn_mfma_f32_16x16x32_bf16(
                            a[i], b[j], acc2[i][j], 0, 0, 0);
            }
            #pragma unroll
            for (int i = 0; i < 2; ++i)
                #pragma unroll
                for (int j = 0; j < 2; ++j)
                    #pragma unroll
                    for (int r = 0; r < 4; ++r)
                        Pc[(size_t)(row0 + (r0t + i) * 16 + quad * 4 + r) * 512 +
                           g * 64 + (c0t + j) * 16 + l16] = __float2half(acc2[i][j][r]);
        }
    }
}

// ---- Kernel 2: out = sum_c P[c] + b2 ----
__global__ __launch_bounds__(256) void k_reduce(const __half* __restrict__ P,
                                                const float* __restrict__ b2,
                                                float* __restrict__ out) {
    int t = blockIdx.x * 256 + threadIdx.x;       // 524288 threads, 4 outputs each
    size_t f = (size_t)t * 4;
    int j = (int)(f & 511);
    float4 s = *reinterpret_cast<const float4*>(&b2[j]);
    #pragma unroll
    for (int c = 0; c < NCH; ++c) {
        const __half2* p = reinterpret_cast<const __half2*>(P + (size_t)c * (NROWS * ODIM) + f);
        float2 a = __half22float2(p[0]);
        float2 b = __half22float2(p[1]);
        s.x += a.x; s.y += a.y; s.z += b.x; s.w += b.y;
    }
    *reinterpret_cast<float4*>(&out[f]) = s;
}

extern "C" void kernel_launch(void* const* d_in, const int* in_sizes, int n_in,
                              void* d_out, int out_size, void* d_ws, size_t ws_size,
                              hipStream_t stream) {
    const float* x  = (const float*)d_in[0];
    const float* W1 = (const float*)d_in[1];
    const float* b1 = (const float*)d_in[2];
    const float* W2 = (const float*)d_in[3];
    const float* b2 = (const float*)d_in[4];
    float* out = (float*)d_out;

    unsigned short* xb  = (unsigned short*)d_ws;                          // 4 MB
    unsigned short* w1t = (unsigned short*)((char*)d_ws + (4u << 20));    // 2 MB
    unsigned short* w2t = (unsigned short*)((char*)d_ws + (6u << 20));    // 2 MB
    __half*         P   = (__half*)((char*)d_ws + (8u << 20));            // 32 MB fp16

    k_prep<<<1536, 256, 0, stream>>>(x, W1, W2, xb, w1t, w2t);
    k_main<<<dim3(NCH, NROWS / TM), 512, 0, stream>>>(xb, w1t, w2t, b1, P);
    k_reduce<<<2048, 256, 0, stream>>>(P, b2, out);
}